// Round 3
// baseline (376.671 us; speedup 1.0000x reference)
//
#include <hip/hip_runtime.h>

#define NPTS 32768
#define G 32
#define NCELL (G*G*G)            // 32768 cells per cloud
#define RANGE 4.5f
#define CELLW (2.0f*RANGE/G)     // 0.28125

typedef unsigned int u32;

// Workspace layout (2 MB total):
//  [0K)    float  mins[65536]      256KB  (per-query min d^2, sorted order - sum is perm-invariant)
//  [256K)  float4 sortedA[32768]   512KB  (pred, counting-sorted by cell)
//  [768K)  float4 sortedB[32768]   512KB  (targ, counting-sorted by cell)
//  [1280K) u32    cnt[2][32768]    256KB  (histogram; also query-time counts)
//  [1536K) u32    cstart[2][32768] 256KB  (exclusive prefix = segment starts)
//  [1792K) u32    cursor[2][32768] 256KB  (scatter cursors, copy of cstart)

__device__ __forceinline__ int cell_of(float v) {
    int c = (int)floorf((v + RANGE) * (G / (2.0f * RANGE)));
    return min(max(c, 0), G - 1);   // outliers clamp to edge cells (bound stays conservative)
}

__global__ __launch_bounds__(256)
void build_hist(const float* __restrict__ pred, const float* __restrict__ targ,
                u32* __restrict__ cnt) {
    int i = blockIdx.x * 256 + threadIdx.x;            // 0..65535
    int cloud = i >> 15, k = i & (NPTS - 1);
    const float* p = cloud ? targ : pred;
    float x = p[3*k], y = p[3*k+1], z = p[3*k+2];
    int c = (cell_of(z) * G + cell_of(y)) * G + cell_of(x);
    atomicAdd(&cnt[cloud * NCELL + c], 1u);
}

// One block per cloud. 1024 threads x 32 cells each: serial run -> wave scan -> block scan.
__global__ __launch_bounds__(1024)
void cell_scan(const u32* __restrict__ cnt, u32* __restrict__ cstart,
               u32* __restrict__ cursor) {
    const u32* c = cnt + blockIdx.x * NCELL;
    u32* st = cstart + blockIdx.x * NCELL;
    u32* cu = cursor + blockIdx.x * NCELL;
    __shared__ u32 wtot[16];
    int t = threadIdx.x, lane = t & 63, wave = t >> 6;
    int base = t * (NCELL / 1024);                     // 32 cells/thread
    u32 loc[NCELL / 1024];
    u32 run = 0;
    #pragma unroll
    for (int k = 0; k < NCELL / 1024; ++k) { loc[k] = run; run += c[base + k]; }
    u32 inc = run;
    #pragma unroll
    for (int off = 1; off < 64; off <<= 1) {
        u32 nv = __shfl_up(inc, off, 64);
        if (lane >= off) inc += nv;
    }
    u32 wex = inc - run;                               // exclusive within wave
    if (lane == 63) wtot[wave] = inc;
    __syncthreads();
    if (t == 0) {
        u32 a = 0;
        #pragma unroll
        for (int w = 0; w < 16; ++w) { u32 v = wtot[w]; wtot[w] = a; a += v; }
    }
    __syncthreads();
    u32 tb = wtot[wave] + wex;
    #pragma unroll
    for (int k = 0; k < NCELL / 1024; ++k) {
        u32 s = tb + loc[k];
        st[base + k] = s; cu[base + k] = s;
    }
}

__global__ __launch_bounds__(256)
void scatter_pts(const float* __restrict__ pred, const float* __restrict__ targ,
                 u32* __restrict__ cursor,
                 float4* __restrict__ sortedA, float4* __restrict__ sortedB) {
    int i = blockIdx.x * 256 + threadIdx.x;
    int cloud = i >> 15, k = i & (NPTS - 1);
    const float* p = cloud ? targ : pred;
    float x = p[3*k], y = p[3*k+1], z = p[3*k+2];
    int c = (cell_of(z) * G + cell_of(y)) * G + cell_of(x);
    u32 pos = atomicAdd(&cursor[cloud * NCELL + c], 1u);
    float4* dst = cloud ? sortedB : sortedA;
    dst[pos] = make_float4(x, y, z, 0.0f);
}

__device__ __forceinline__ void scan_cell(int c, const u32* cs, const u32* cc,
                                          const float4* __restrict__ T,
                                          float4 q, float& best) {
    u32 s = cs[c], n = cc[c];
    for (u32 e = s; e < s + n; ++e) {
        float4 t = T[e];
        float dx = q.x - t.x, dy = q.y - t.y, dz = q.z - t.z;
        float d = fmaf(dx, dx, fmaf(dy, dy, dz * dz));
        best = fminf(best, d);
    }
}

// Exact NN via expanding Chebyshev shells. After shell r completes, every
// unvisited point differs by >= r+1 cells in some dim => distance >= r*CELLW
// (conservative also for clamped outliers). Queries in sorted order => wave-
// coherent cells; result written to sorted slot (sum is permutation-invariant).
__global__ __launch_bounds__(256)
void query_min(const float4* __restrict__ sortedA, const float4* __restrict__ sortedB,
               const u32* __restrict__ cstart, const u32* __restrict__ cnt,
               float* __restrict__ outmins) {
    int i = blockIdx.x * 256 + threadIdx.x;            // 0..65535
    int cloud = i >> 15, k = i & (NPTS - 1);
    const float4* Q = cloud ? sortedB : sortedA;
    const float4* T = cloud ? sortedA : sortedB;
    int tg = cloud ^ 1;                                // target grid = other cloud's
    const u32* cs = cstart + tg * NCELL;
    const u32* cc = cnt    + tg * NCELL;

    float4 q = Q[k];
    int cx = cell_of(q.x), cy = cell_of(q.y), cz = cell_of(q.z);
    float best = 3.4e38f;

    for (int r = 0; r < G; ++r) {
        if (r >= 1) {
            float lb = (float)(r - 1) * CELLW;
            bool need = best > lb * lb;
            if (!__any(need)) break;                   // wave-uniform exit
            if (!need) continue;                       // lane-masked skip
        }
        int x0 = max(cx - r, 0), x1 = min(cx + r, G - 1);
        int y0 = max(cy - r, 0), y1 = min(cy + r, G - 1);
        int z0 = max(cz - r, 0), z1 = min(cz + r, G - 1);
        for (int z = z0; z <= z1; ++z) {
            int zface = (z == cz - r) || (z == cz + r);
            for (int y = y0; y <= y1; ++y) {
                int face = zface || (y == cy - r) || (y == cy + r);
                int rowbase = (z * G + y) * G;
                if (face) {
                    for (int x = x0; x <= x1; ++x)
                        scan_cell(rowbase + x, cs, cc, T, q, best);
                } else {                               // interior row: only the two x-faces
                    if (cx - r >= 0)     scan_cell(rowbase + cx - r, cs, cc, T, q, best);
                    if (cx + r <= G - 1) scan_cell(rowbase + cx + r, cs, cc, T, q, best);
                }
            }
        }
    }
    outmins[i] = best;
}

// Sum all 65536 per-point mins; out = sum / 32768 (= mean1 + mean2).
__global__ __launch_bounds__(256)
void reduce_mean(const float* __restrict__ mins, float* __restrict__ out) {
    float sum = 0.0f;
    for (int i = blockIdx.x * blockDim.x + threadIdx.x; i < 2 * NPTS;
         i += gridDim.x * blockDim.x)
        sum += mins[i];
    #pragma unroll
    for (int off = 32; off > 0; off >>= 1)
        sum += __shfl_down(sum, off, 64);
    __shared__ float wsum[4];
    int lane = threadIdx.x & 63, wave = threadIdx.x >> 6;
    if (lane == 0) wsum[wave] = sum;
    __syncthreads();
    if (threadIdx.x == 0) {
        float s = wsum[0] + wsum[1] + wsum[2] + wsum[3];
        atomicAdd(out, s * (1.0f / NPTS));
    }
}

extern "C" void kernel_launch(void* const* d_in, const int* in_sizes, int n_in,
                              void* d_out, int out_size, void* d_ws, size_t ws_size,
                              hipStream_t stream) {
    const float* pred = (const float*)d_in[0];
    const float* targ = (const float*)d_in[1];
    float* out = (float*)d_out;

    char* ws = (char*)d_ws;
    float*  mins    = (float*) (ws);
    float4* sortedA = (float4*)(ws + (256 << 10));
    float4* sortedB = (float4*)(ws + (768 << 10));
    u32*    cnt     = (u32*)   (ws + (1280 << 10));
    u32*    cstart  = (u32*)   (ws + (1536 << 10));
    u32*    cursor  = (u32*)   (ws + (1792 << 10));

    hipMemsetAsync(cnt, 0, 2 * NCELL * sizeof(u32), stream);
    hipMemsetAsync(d_out, 0, sizeof(float), stream);

    build_hist <<<256, 256, 0, stream>>>(pred, targ, cnt);
    cell_scan  <<<2, 1024, 0, stream>>>(cnt, cstart, cursor);
    scatter_pts<<<256, 256, 0, stream>>>(pred, targ, cursor, sortedA, sortedB);
    query_min  <<<256, 256, 0, stream>>>(sortedA, sortedB, cstart, cnt, mins);
    reduce_mean<<<64, 256, 0, stream>>>(mins, out);
}

// Round 4
// 331.728 us; speedup vs baseline: 1.1355x; 1.1355x over previous
//
#include <hip/hip_runtime.h>
#include <hip/hip_cooperative_groups.h>
namespace cg = cooperative_groups;

#define NPTS 32768
#define G 32
#define NCELL (G*G*G)          // 32768 cells per cloud
#define SSTR  32896            // NCELL+1, padded
#define RANGE 4.5f
#define CELLW (2.0f*RANGE/G)   // 0.28125 -- exactly representable (9/32)

typedef unsigned int u32;

// Workspace layout:
//  [0K)     float4 sortedA[32768]   512KB   pred, counting-sorted by cell
//  [512K)   float4 sortedB[32768]   512KB   targ, counting-sorted by cell
//  [1024K)  u32    S[2][SSTR]       257KB   exclusive scan (+terminator NPTS)
//  [1344K)  u32    cnt[2][NCELL]    256KB   histogram
//  [1600K)  u32    cursor[2][NCELL] 256KB   scatter cursors
//  [1856K)  u32    bt[256]          1KB     block totals for global scan

__device__ __forceinline__ int cell_of(float v) {
    int c = (int)floorf((v + RANGE) * (G / (2.0f * RANGE)));
    return min(max(c, 0), G - 1);   // outliers clamp inward -> bounds stay conservative
}
__device__ __forceinline__ float cell_lo(int i) {   // exact: i*(9/32) - 4.5
    return fmaf((float)i, CELLW, -RANGE);
}

// ---- One cooperative kernel: zero -> histogram -> global scan -> scatter ----
__global__ __launch_bounds__(256)
void build_all(const float* __restrict__ pred, const float* __restrict__ targ,
               float4* __restrict__ sortedA, float4* __restrict__ sortedB,
               u32* __restrict__ S, u32* __restrict__ cnt, u32* __restrict__ cursor,
               u32* __restrict__ bt, float* __restrict__ out) {
    cg::grid_group grid = cg::this_grid();
    int gtid = blockIdx.x * 256 + threadIdx.x;       // 0..65535 == 2*NCELL
    int lane = threadIdx.x & 63, wave = threadIdx.x >> 6;
    __shared__ u32 wt[4];

    // phase 0: zero histogram + output
    cnt[gtid] = 0;
    if (gtid == 0) *out = 0.0f;
    grid.sync();

    // phase 1: histogram (one point per thread, both clouds)
    {
        int cloud = gtid >> 15, k = gtid & (NPTS - 1);
        const float* p = cloud ? targ : pred;
        float x = p[3*k], y = p[3*k+1], z = p[3*k+2];
        int c = (cell_of(z) * G + cell_of(y)) * G + cell_of(x);
        atomicAdd(&cnt[cloud * NCELL + c], 1u);
    }
    grid.sync();

    // phase 2a: per-block scan of 256 cells
    u32 val = cnt[gtid];
    u32 inc = val;
    #pragma unroll
    for (int off = 1; off < 64; off <<= 1) {
        u32 nv = __shfl_up(inc, off, 64);
        if (lane >= off) inc += nv;
    }
    u32 wex = inc - val;
    if (lane == 63) wt[wave] = inc;
    __syncthreads();
    if (threadIdx.x == 0) {
        u32 a = 0;
        #pragma unroll
        for (int w = 0; w < 4; ++w) { u32 v = wt[w]; wt[w] = a; a += v; }
    }
    __syncthreads();
    u32 exb = wt[wave] + wex;                        // exclusive within block
    if (threadIdx.x == 255) bt[blockIdx.x] = exb + val;
    grid.sync();

    // phase 2b: block 0 scans the 256 block totals (exclusive)
    if (blockIdx.x == 0) {
        u32 bv = bt[threadIdx.x];
        u32 binc = bv;
        #pragma unroll
        for (int off = 1; off < 64; off <<= 1) {
            u32 nv = __shfl_up(binc, off, 64);
            if (lane >= off) binc += nv;
        }
        u32 bwex = binc - bv;
        if (lane == 63) wt[wave] = binc;
        __syncthreads();
        if (threadIdx.x == 0) {
            u32 a = 0;
            #pragma unroll
            for (int w = 0; w < 4; ++w) { u32 v = wt[w]; wt[w] = a; a += v; }
        }
        __syncthreads();
        bt[threadIdx.x] = wt[wave] + bwex;
    }
    grid.sync();

    // phase 2c: write S (per-cloud rebased) + cursor
    u32 gex = bt[blockIdx.x] + exb;
    {
        int cloud = gtid >> 15;
        u32 sv = gex - (cloud ? NPTS : 0);           // cloud A total == NPTS exactly
        S[cloud * SSTR + (gtid & (NCELL - 1))] = sv;
        cursor[gtid] = sv;
        if (gtid == 0) { S[NCELL] = NPTS; S[SSTR + NCELL] = NPTS; }
    }
    grid.sync();

    // phase 3: scatter points into cell-sorted order
    {
        int cloud = gtid >> 15, k = gtid & (NPTS - 1);
        const float* p = cloud ? targ : pred;
        float x = p[3*k], y = p[3*k+1], z = p[3*k+2];
        int c = (cell_of(z) * G + cell_of(y)) * G + cell_of(x);
        u32 pos = atomicAdd(&cursor[cloud * NCELL + c], 1u);
        (cloud ? sortedB : sortedA)[pos] = make_float4(x, y, z, 0.0f);
    }
}

// ---- Query: 8 lanes per query, pruned neighbor cells, fused mean-reduce ----
__global__ __launch_bounds__(256, 8)
void query_min(const float4* __restrict__ sortedA, const float4* __restrict__ sortedB,
               const u32* __restrict__ Sall, float* __restrict__ out) {
    int tid = blockIdx.x * 256 + threadIdx.x;        // 0..524287
    int sub = tid & 7;
    int qi = tid >> 3;                               // 0..65535
    int cloud = qi >> 15, k = qi & (NPTS - 1);
    const float4* Q = cloud ? sortedB : sortedA;
    const float4* T = cloud ? sortedA : sortedB;
    const u32* s = Sall + (cloud ^ 1) * SSTR;        // other cloud's grid

    float4 q = Q[k];
    int cx = cell_of(q.x), cy = cell_of(q.y), cz = cell_of(q.z);
    float best = 3.4e38f;

    auto scan_seg = [&](u32 beg, u32 end) {
        for (u32 e = beg + sub; e < end; e += 8) {   // 8-lane interleave: 128B coalesced
            float4 t = T[e];
            float dx = q.x - t.x, dy = q.y - t.y, dz = q.z - t.z;
            best = fminf(best, fmaf(dx, dx, fmaf(dy, dy, dz * dz)));
        }
    };
    auto group_min = [&]() {                          // 8-lane group reduce
        best = fminf(best, __shfl_xor(best, 1, 64));
        best = fminf(best, __shfl_xor(best, 2, 64));
        best = fminf(best, __shfl_xor(best, 4, 64));
    };

    // own cell first (densest prior)
    {
        int c0 = (cz * G + cy) * G + cx;
        scan_seg(s[c0], s[c0 + 1]);
    }
    group_min();

    // 26 neighbors, faces -> edges -> corners, pruned by exact box distance.
    // Skipped cell had mind2 >= best-at-skip >= final best: exactness preserved.
    const int NBx[26] = { 1,-1, 0, 0, 0, 0,  1, 1,-1,-1, 1, 1,-1,-1, 0, 0, 0, 0,  1, 1, 1, 1,-1,-1,-1,-1};
    const int NBy[26] = { 0, 0, 1,-1, 0, 0,  1,-1, 1,-1, 0, 0, 0, 0, 1, 1,-1,-1,  1, 1,-1,-1, 1, 1,-1,-1};
    const int NBz[26] = { 0, 0, 0, 0, 1,-1,  0, 0, 0, 0, 1,-1, 1,-1, 1,-1, 1,-1,  1,-1, 1,-1, 1,-1, 1,-1};
    #pragma unroll
    for (int i = 0; i < 26; ++i) {
        int X = cx + NBx[i], Y = cy + NBy[i], Z = cz + NBz[i];
        if ((unsigned)X >= G || (unsigned)Y >= G || (unsigned)Z >= G) continue;
        float ex = NBx[i] > 0 ? cell_lo(X) - q.x : (NBx[i] < 0 ? q.x - cell_lo(X + 1) : 0.0f);
        float ey = NBy[i] > 0 ? cell_lo(Y) - q.y : (NBy[i] < 0 ? q.y - cell_lo(Y + 1) : 0.0f);
        float ez = NBz[i] > 0 ? cell_lo(Z) - q.z : (NBz[i] < 0 ? q.z - cell_lo(Z + 1) : 0.0f);
        float mind2 = fmaf(ex, ex, fmaf(ey, ey, ez * ez));
        if (mind2 < best) {                           // group-uniform (same q per group)
            int c = (Z * G + Y) * G + X;
            scan_seg(s[c], s[c + 1]);
            group_min();
        }
    }

    // rare fallback: expanding shells. Bound = distance from q to scanned-box
    // boundary; domain-edge faces contribute nothing (points clamp inward).
    for (int r = 2; r < G; ++r) {
        int rr = r - 1;
        float bd = 3.4e38f;
        if (cx - rr > 0)     bd = fminf(bd, q.x - cell_lo(cx - rr));
        if (cx + rr < G - 1) bd = fminf(bd, cell_lo(cx + rr + 1) - q.x);
        if (cy - rr > 0)     bd = fminf(bd, q.y - cell_lo(cy - rr));
        if (cy + rr < G - 1) bd = fminf(bd, cell_lo(cy + rr + 1) - q.y);
        if (cz - rr > 0)     bd = fminf(bd, q.z - cell_lo(cz - rr));
        if (cz + rr < G - 1) bd = fminf(bd, cell_lo(cz + rr + 1) - q.z);
        if (best <= bd * bd) break;

        int zlo = max(cz - r, 0), zhi = min(cz + r, G - 1);
        int ylo = max(cy - r, 0), yhi = min(cy + r, G - 1);
        int xlo = max(cx - r, 0), xhi = min(cx + r, G - 1);
        for (int z = zlo; z <= zhi; ++z) {
            bool zf = (z == cz - r) || (z == cz + r);
            for (int y = ylo; y <= yhi; ++y) {
                int cb = (z * G + y) * G;
                if (zf || y == cy - r || y == cy + r) {
                    scan_seg(s[cb + xlo], s[cb + xhi + 1]);   // contiguous x-run
                } else {
                    if (cx - r >= 0)     scan_seg(s[cb + cx - r], s[cb + cx - r + 1]);
                    if (cx + r <= G - 1) scan_seg(s[cb + cx + r], s[cb + cx + r + 1]);
                }
            }
        }
        group_min();
    }

    // fused mean: each query's best is replicated on its 8 lanes -> weight 1/8
    float v = best * 0.125f;
    #pragma unroll
    for (int off = 1; off < 64; off <<= 1)
        v += __shfl_xor(v, off, 64);
    __shared__ float wsum[4];
    int lane = threadIdx.x & 63, wave = threadIdx.x >> 6;
    if (lane == 0) wsum[wave] = v;
    __syncthreads();
    if (threadIdx.x == 0)
        atomicAdd(out, (wsum[0] + wsum[1] + wsum[2] + wsum[3]) * (1.0f / NPTS));
}

extern "C" void kernel_launch(void* const* d_in, const int* in_sizes, int n_in,
                              void* d_out, int out_size, void* d_ws, size_t ws_size,
                              hipStream_t stream) {
    const float* pred = (const float*)d_in[0];
    const float* targ = (const float*)d_in[1];
    float* out = (float*)d_out;
    char* ws = (char*)d_ws;
    float4* sortedA = (float4*)(ws);
    float4* sortedB = (float4*)(ws + (512 << 10));
    u32* S      = (u32*)(ws + (1024 << 10));
    u32* cnt    = (u32*)(ws + (1344 << 10));
    u32* cursor = (u32*)(ws + (1600 << 10));
    u32* bt     = (u32*)(ws + (1856 << 10));

    void* args[] = {(void*)&pred, (void*)&targ, (void*)&sortedA, (void*)&sortedB,
                    (void*)&S, (void*)&cnt, (void*)&cursor, (void*)&bt, (void*)&out};
    hipLaunchCooperativeKernel((void*)build_all, dim3(256), dim3(256), args, 0, stream);
    query_min<<<2048, 256, 0, stream>>>(sortedA, sortedB, S, out);
}

// Round 5
// 295.558 us; speedup vs baseline: 1.2744x; 1.1224x over previous
//
#include <hip/hip_runtime.h>

#define NPTS 32768
#define G 32
#define NCELL (G*G*G)          // 32768 cells per cloud
#define SSTR (NCELL + 1)
#define RANGE 4.5f
#define CELLW 0.28125f         // 9/32, exact in fp32

typedef unsigned int u32;

// Workspace layout:
//  [0K)     float4 sortedA[32768]   512KB   pred, counting-sorted by cell
//  [512K)   float4 sortedB[32768]   512KB   targ, counting-sorted by cell
//  [1024K)  u32    S[2][SSTR]       257KB   exclusive scan (+terminator NPTS)
//  [1344K)  u32    cursor[2][NCELL] 256KB   scatter cursors

__device__ __forceinline__ int cell_of(float v) {
    int c = (int)floorf((v + RANGE) * (G / (2.0f * RANGE)));
    return min(max(c, 0), G - 1);   // outliers clamp inward -> all bounds stay conservative
}
__device__ __forceinline__ float cell_lo(int i) {   // exact: i*(9/32) - 4.5
    return fmaf((float)i, CELLW, -RANGE);
}

// ---- Build: ONE plain dispatch, one 1024-thread block per cloud. ----
// LDS u16-packed histogram (64KB) -> shuffle scan -> S/cursor -> scatter.
__global__ __launch_bounds__(1024)
void build_sort(const float* __restrict__ pred, const float* __restrict__ targ,
                float4* __restrict__ sortedA, float4* __restrict__ sortedB,
                u32* __restrict__ S, u32* __restrict__ cursor, float* __restrict__ out) {
    __shared__ u32 hist[NCELL / 2];   // 2 u16 counts per word; max cell count << 65536
    __shared__ u32 wt[16];
    int cloud = blockIdx.x;
    const float* p = cloud ? targ : pred;
    float4* dst = cloud ? sortedB : sortedA;
    u32* s   = S + cloud * SSTR;
    u32* cur = cursor + cloud * NCELL;
    int t = threadIdx.x, lane = t & 63, wave = t >> 6;

    if (cloud == 0 && t == 0) *out = 0.0f;    // re-zeroed every graph replay

    #pragma unroll
    for (int k = 0; k < NCELL / 2 / 1024; ++k) hist[t + k * 1024] = 0;
    __syncthreads();

    // histogram: packed u16 add (no carry: per-cell count <= NPTS < 65536)
    #pragma unroll
    for (int k = 0; k < NPTS / 1024; ++k) {
        int i = t + k * 1024;
        float x = p[3*i], y = p[3*i+1], z = p[3*i+2];
        int c = (cell_of(z) * G + cell_of(y)) * G + cell_of(x);
        atomicAdd(&hist[c >> 1], 1u << ((c & 1) * 16));
    }
    __syncthreads();

    // scan: thread t owns words [16t,16t+16) == cells [32t,32t+32)
    u32 run = 0;
    #pragma unroll
    for (int k = 0; k < 16; ++k) {
        u32 w = hist[16 * t + k];
        run += (w & 0xffffu) + (w >> 16);
    }
    u32 inc = run;
    #pragma unroll
    for (int off = 1; off < 64; off <<= 1) {
        u32 nv = __shfl_up(inc, off, 64);
        if (lane >= off) inc += nv;
    }
    if (lane == 63) wt[wave] = inc;
    __syncthreads();
    if (t == 0) {
        u32 a = 0;
        #pragma unroll
        for (int w = 0; w < 16; ++w) { u32 v = wt[w]; wt[w] = a; a += v; }
    }
    __syncthreads();
    u32 tb = wt[wave] + (inc - run);          // global exclusive base for cell 32t
    #pragma unroll
    for (int k = 0; k < 16; ++k) {
        u32 w = hist[16 * t + k];
        u32 lo = w & 0xffffu, hi = w >> 16;
        int c = 32 * t + 2 * k;
        s[c] = tb;        cur[c] = tb;
        s[c+1] = tb + lo; cur[c+1] = tb + lo;
        tb += lo + hi;
    }
    if (t == 1023) s[NCELL] = NPTS;
    __threadfence();                          // cursor writes -> L2 before block atomics
    __syncthreads();

    // scatter into cell-sorted order
    #pragma unroll
    for (int k = 0; k < NPTS / 1024; ++k) {
        int i = t + k * 1024;
        float x = p[3*i], y = p[3*i+1], z = p[3*i+2];
        int c = (cell_of(z) * G + cell_of(y)) * G + cell_of(x);
        u32 pos = atomicAdd(&cur[c], 1u);
        dst[pos] = make_float4(x, y, z, 0.0f);
    }
}

// ---- Query: 8 lanes/query; 27-box as 9 contiguous x-runs; 2 latency rounds. ----
__global__ __launch_bounds__(256, 8)
void query_min(const float4* __restrict__ sortedA, const float4* __restrict__ sortedB,
               const u32* __restrict__ Sall, float* __restrict__ out) {
    int tid = blockIdx.x * 256 + threadIdx.x;        // 0..524287
    int sub = tid & 7;
    int qi = tid >> 3;                               // 0..65535
    int cloud = qi >> 15, k = qi & (NPTS - 1);
    const float4* Q = cloud ? sortedB : sortedA;
    const float4* T = cloud ? sortedA : sortedB;
    const u32* s = Sall + (cloud ^ 1) * SSTR;        // other cloud's grid

    float4 q = Q[k];
    int cx = cell_of(q.x), cy = cell_of(q.y), cz = cell_of(q.z);
    int x0 = max(cx - 1, 0), x1 = min(cx + 1, G - 1);
    float best = 3.4e38f;

    // center-row descriptors + all 8 neighbor-row descriptors: issue early, independent
    int cbc = (cz * G + cy) * G;
    u32 cbeg = s[cbc + x0], cend = s[cbc + x1 + 1];
    u32 rb[9], re[9];
    #pragma unroll
    for (int i = 0; i < 9; ++i) {
        int dy = (i % 3) - 1, dz = (i / 3) - 1;
        int Y = cy + dy, Z = cz + dz;
        rb[i] = 0; re[i] = 0;
        if (i != 4 && (unsigned)Y < G && (unsigned)Z < G) {
            int cb = (Z * G + Y) * G;
            rb[i] = s[cb + x0]; re[i] = s[cb + x1 + 1];
        }
    }

    auto scan_seg = [&](u32 beg, u32 end) {
        for (u32 e = beg + sub; e < end; e += 8) {   // 8 lanes: 128B-coalesced iters
            float4 t = T[e];
            float dx = q.x - t.x, dy = q.y - t.y, dz = q.z - t.z;
            best = fminf(best, fmaf(dx, dx, fmaf(dy, dy, dz * dz)));
        }
    };
    auto group_min = [&]() {
        best = fminf(best, __shfl_xor(best, 1, 64));
        best = fminf(best, __shfl_xor(best, 2, 64));
        best = fminf(best, __shfl_xor(best, 4, 64));
    };

    // round 1: center row (contains own cell)
    scan_seg(cbeg, cend);
    group_min();

    // round 2: prune rows against the post-center best ONCE, scan survivors.
    // Pruned row: mind2 >= best-at-prune >= final best -> exact.
    #pragma unroll
    for (int i = 0; i < 9; ++i) {
        if (i == 4) continue;
        int dy = (i % 3) - 1, dz = (i / 3) - 1;
        int Y = cy + dy, Z = cz + dz;
        if ((unsigned)Y >= G || (unsigned)Z >= G) continue;
        float ey = dy > 0 ? cell_lo(Y) - q.y : q.y - cell_lo(Y + 1);
        float ez = dz > 0 ? cell_lo(Z) - q.z : q.z - cell_lo(Z + 1);
        if (dy == 0) ey = 0.0f;
        if (dz == 0) ez = 0.0f;
        float mind2 = fmaf(ey, ey, ez * ez);
        if (mind2 < best) scan_seg(rb[i], re[i]);    // group-uniform branch
    }
    group_min();

    // box-completeness bound (domain-edge faces: nothing beyond, points clamp inward)
    float bd = 3.4e38f;
    if (cx - 1 > 0)     bd = fminf(bd, q.x - cell_lo(cx - 1));
    if (cx + 1 < G - 1) bd = fminf(bd, cell_lo(cx + 2) - q.x);
    if (cy - 1 > 0)     bd = fminf(bd, q.y - cell_lo(cy - 1));
    if (cy + 1 < G - 1) bd = fminf(bd, cell_lo(cy + 2) - q.y);
    if (cz - 1 > 0)     bd = fminf(bd, q.z - cell_lo(cz - 1));
    if (cz + 1 < G - 1) bd = fminf(bd, cell_lo(cz + 2) - q.z);

    if (best > bd * bd) {
        // rare fallback: expanding shells (exact, conservative under clamping)
        for (int r = 2; r < G; ++r) {
            int rr = r - 1;
            float b2 = 3.4e38f;
            if (cx - rr > 0)     b2 = fminf(b2, q.x - cell_lo(cx - rr));
            if (cx + rr < G - 1) b2 = fminf(b2, cell_lo(cx + rr + 1) - q.x);
            if (cy - rr > 0)     b2 = fminf(b2, q.y - cell_lo(cy - rr));
            if (cy + rr < G - 1) b2 = fminf(b2, cell_lo(cy + rr + 1) - q.y);
            if (cz - rr > 0)     b2 = fminf(b2, q.z - cell_lo(cz - rr));
            if (cz + rr < G - 1) b2 = fminf(b2, cell_lo(cz + rr + 1) - q.z);
            if (best <= b2 * b2) break;

            int zlo = max(cz - r, 0), zhi = min(cz + r, G - 1);
            int ylo = max(cy - r, 0), yhi = min(cy + r, G - 1);
            int xlo = max(cx - r, 0), xhi = min(cx + r, G - 1);
            for (int z = zlo; z <= zhi; ++z) {
                bool zf = (z == cz - r) || (z == cz + r);
                for (int y = ylo; y <= yhi; ++y) {
                    int cb = (z * G + y) * G;
                    if (zf || y == cy - r || y == cy + r) {
                        scan_seg(s[cb + xlo], s[cb + xhi + 1]);   // contiguous x-run
                    } else {
                        if (cx - r >= 0)     scan_seg(s[cb + cx - r], s[cb + cx - r + 1]);
                        if (cx + r <= G - 1) scan_seg(s[cb + cx + r], s[cb + cx + r + 1]);
                    }
                }
            }
            group_min();
        }
    }

    // fused mean: each query's best replicated on its 8 lanes -> weight 1/8
    float v = best * 0.125f;
    #pragma unroll
    for (int off = 1; off < 64; off <<= 1)
        v += __shfl_xor(v, off, 64);
    __shared__ float wsum[4];
    int lane = threadIdx.x & 63, wave = threadIdx.x >> 6;
    if (lane == 0) wsum[wave] = v;
    __syncthreads();
    if (threadIdx.x == 0)
        atomicAdd(out, (wsum[0] + wsum[1] + wsum[2] + wsum[3]) * (1.0f / NPTS));
}

extern "C" void kernel_launch(void* const* d_in, const int* in_sizes, int n_in,
                              void* d_out, int out_size, void* d_ws, size_t ws_size,
                              hipStream_t stream) {
    const float* pred = (const float*)d_in[0];
    const float* targ = (const float*)d_in[1];
    float* out = (float*)d_out;
    char* ws = (char*)d_ws;
    float4* sortedA = (float4*)(ws);
    float4* sortedB = (float4*)(ws + (512 << 10));
    u32* S      = (u32*)(ws + (1024 << 10));
    u32* cursor = (u32*)(ws + (1344 << 10));

    build_sort<<<2, 1024, 0, stream>>>(pred, targ, sortedA, sortedB, S, cursor, out);
    query_min <<<2048, 256, 0, stream>>>(sortedA, sortedB, S, out);
}